// Round 10
// baseline (216.931 us; speedup 1.0000x reference)
//
#include <hip/hip_runtime.h>
#include <hip/hip_bf16.h>
#include <stdint.h>

#define B_   4
#define T_   2048
#define H_   8
#define HD_  64
#define DM_  512
#define N3_  1536

typedef short bf_el;
typedef __attribute__((ext_vector_type(8))) bf_el bfrag;   // 8 bf16 = 4 VGPRs
typedef __attribute__((ext_vector_type(4))) float ffrag;

#define SCALE_L2E  0.18033688011112043f   /* 0.125 * log2(e) */
#define MASK_L2E   14426.950408889634f    /* 1e4  * log2(e) */

static __device__ __forceinline__ unsigned short f2bf(float f) {      // RNE
    union { float f; unsigned int i; } v; v.f = f;
    unsigned int r = v.i + 0x7fff + ((v.i >> 16) & 1);
    return (unsigned short)(r >> 16);
}
static __device__ __forceinline__ unsigned short f2bf_fast(float f) { // round-half-up
    union { float f; unsigned int i; } v; v.f = f;
    return (unsigned short)((v.i + 0x8000u) >> 16);
}

// ---------------------------------------------------------------------------
// Kernel 0 (prep, 3 BW-bound roles by blockIdx.x):
//  [0,512)  : mask scan, contiguous 128KB/block -> flags4[e][kt][part]
//             written UNCONDITIONALLY (no memset, no atomics needed)
//  [512,768): X fp32 -> bf16
//  [768,960): W [512,1536] fp32 -> Wt bf16 [1536,512]
// ---------------------------------------------------------------------------
__global__ __launch_bounds__(256) void k_prep(const float* __restrict__ W,
                                              const float* __restrict__ X,
                                              const float* __restrict__ mask,
                                              unsigned short* __restrict__ Wt,
                                              unsigned short* __restrict__ Xb,
                                              int* __restrict__ flags4) {
    __shared__ __align__(16) unsigned short Ls[64 * 72];
    const int bid = blockIdx.x;
    const int tid = threadIdx.x;

    if (bid < 512) {
        // ---- mask scan: 16 consecutive mask rows per block (128 KB) ----
        const int R0 = bid * 16;              // global row in [0, 8192)
        const int mb = R0 >> 11;              // batch
        const int q0 = R0 & 2047;
        const int e  = mb * 32 + (q0 >> 6);   // flag row  (b*32 + qt64)
        const int part = (R0 >> 4) & 3;       // which 16-row quarter of the 64-q tile
        const int wave = tid >> 6, lane = tid & 63;
        unsigned int acc = 0u;
        const float* base = mask + (size_t)R0 * T_ + tid * 8;
#pragma unroll
        for (int rr = 0; rr < 16; ++rr) {
            const uint4 u0 = *(const uint4*)(base + (size_t)rr * T_);
            const uint4 u1 = *(const uint4*)(base + (size_t)rr * T_ + 4);
            acc |= (u0.x ^ 0x3F800000u) | (u0.y ^ 0x3F800000u) |
                   (u0.z ^ 0x3F800000u) | (u0.w ^ 0x3F800000u) |
                   (u1.x ^ 0x3F800000u) | (u1.y ^ 0x3F800000u) |
                   (u1.z ^ 0x3F800000u) | (u1.w ^ 0x3F800000u);
        }
        unsigned long long bal = __ballot(acc != 0u);   // byte j of wave w = kt 8w+j
        if (lane < 8) {
            const int kt = wave * 8 + lane;
            flags4[(e * 32 + kt) * 4 + part] = ((bal >> (8 * lane)) & 0xFFULL) ? 1 : 0;
        }
        return;
    }
    if (bid < 768) {
        // ---- X convert: 16384 floats per block ----
        const int b2 = bid - 512;
        const float* src = X + (size_t)b2 * 16384;
        unsigned short* dst = Xb + (size_t)b2 * 16384;
#pragma unroll
        for (int j = 0; j < 8; ++j) {
            int idx = j * 512 + tid * 2;
            float4 f0 = *(const float4*)(src + idx * 4);
            float4 f1 = *(const float4*)(src + idx * 4 + 4);
            __align__(16) unsigned short t8[8];
            t8[0] = f2bf_fast(f0.x); t8[1] = f2bf_fast(f0.y);
            t8[2] = f2bf_fast(f0.z); t8[3] = f2bf_fast(f0.w);
            t8[4] = f2bf_fast(f1.x); t8[5] = f2bf_fast(f1.y);
            t8[6] = f2bf_fast(f1.z); t8[7] = f2bf_fast(f1.w);
            *(uint4*)(dst + idx * 4) = *(const uint4*)t8;
        }
        return;
    }
    // ---- W transpose+convert ----
    {
        const int t  = bid - 768;                 // 0..191 = 24 x 8
        const int n0 = (t % 24) * 64;
        const int k0 = (t / 24) * 64;
#pragma unroll
        for (int i = 0; i < 4; ++i) {
            int chunk = tid + i * 256;
            int k = chunk >> 4;
            int c = chunk & 15;
            float4 f = *(const float4*)(W + (size_t)(k0 + k) * N3_ + n0 + c * 4);
            unsigned short* p = Ls + k * 72 + c * 4;
            p[0] = f2bf(f.x); p[1] = f2bf(f.y); p[2] = f2bf(f.z); p[3] = f2bf(f.w);
        }
        __syncthreads();
        const int n = tid >> 2;
        const int g = tid & 3;
        __align__(16) unsigned short tmp[16];
#pragma unroll
        for (int i = 0; i < 16; ++i) tmp[i] = Ls[(g * 16 + i) * 72 + n];
        uint4* dst = (uint4*)(Wt + (size_t)(n0 + n) * DM_ + k0 + g * 16);
        dst[0] = *(const uint4*)(tmp);
        dst[1] = *(const uint4*)(tmp + 8);
    }
}

// ---------------------------------------------------------------------------
// Kernel 1: Xb bf16 [8192,512] @ Wt^T + bias -> Q(pre-scaled)/K/Vt bf16.
// 64(m) x 192(n) tile = one head, slim acc (48 VGPR). Grid 1024, flat
// bid = h*128 + mt so XCD = mt%8: A-tile L2-shared by all 8 heads.
// Register-prefetch of kt+1 issued under the MFMA block.
// ---------------------------------------------------------------------------
__global__ __launch_bounds__(256, 4) void k_gemm_qkv(const unsigned short* __restrict__ Xb,
                                                     const unsigned short* __restrict__ Wt,
                                                     const float* __restrict__ bias,
                                                     unsigned short* __restrict__ Qb,
                                                     unsigned short* __restrict__ Kb,
                                                     unsigned short* __restrict__ Vtb) {
    // union: staging As[64*40](2560) + Bs[192*40](7680) == epilogue Cs[64*200](12800)
    __shared__ __align__(16) unsigned short SH[12800];
    unsigned short* As = SH;            // row stride 40 shorts (32 data + 8 pad)
    unsigned short* Bs = SH + 2560;
    unsigned short* Cs = SH;            // row stride 200 shorts (192 data + 8 pad)

    const int tid  = threadIdx.x;
    const int wave = tid >> 6;
    const int lane = tid & 63;
    const int quad = lane >> 4;
    const int l16  = lane & 15;
    const int wm = wave >> 1, wn = wave & 1;    // 2x2 waves: 32 rows x 96 cols each
    const int h  = blockIdx.x >> 7;             // head
    const int m0 = (blockIdx.x & 127) * 64;
    const int n0 = h * 192;

    float bvv[6];
#pragma unroll
    for (int ni = 0; ni < 6; ++ni) bvv[ni] = bias[n0 + wn * 96 + ni * 16 + l16];

    ffrag acc[2][6];
#pragma unroll
    for (int i = 0; i < 2; ++i)
#pragma unroll
        for (int j = 0; j < 6; ++j) acc[i][j] = (ffrag){0.f, 0.f, 0.f, 0.f};

    // staging assignments: A 256 chunks (1/thread), B 768 chunks (3/thread)
    const int ar = tid >> 2, ac = tid & 3;
    const int br0 = tid >> 2, br1 = (tid + 256) >> 2, br2 = (tid + 512) >> 2;
    const int bc  = tid & 3;
    uint4 pa, pb0, pb1, pb2;

    // preload kt = 0
    pa  = *(const uint4*)(Xb + (size_t)(m0 + ar) * DM_ + ac * 8);
    pb0 = *(const uint4*)(Wt + (size_t)(n0 + br0) * DM_ + bc * 8);
    pb1 = *(const uint4*)(Wt + (size_t)(n0 + br1) * DM_ + bc * 8);
    pb2 = *(const uint4*)(Wt + (size_t)(n0 + br2) * DM_ + bc * 8);

    for (int kt = 0; kt < 16; ++kt) {
        __syncthreads();                         // prior-iter frag reads done
        *(uint4*)(As + ar * 40 + ac * 8)  = pa;
        *(uint4*)(Bs + br0 * 40 + bc * 8) = pb0;
        *(uint4*)(Bs + br1 * 40 + bc * 8) = pb1;
        *(uint4*)(Bs + br2 * 40 + bc * 8) = pb2;
        __syncthreads();
        if (kt < 15) {                           // prefetch kt+1 under the MFMAs
            const int ko = (kt + 1) * 32;
            pa  = *(const uint4*)(Xb + (size_t)(m0 + ar) * DM_ + ko + ac * 8);
            pb0 = *(const uint4*)(Wt + (size_t)(n0 + br0) * DM_ + ko + bc * 8);
            pb1 = *(const uint4*)(Wt + (size_t)(n0 + br1) * DM_ + ko + bc * 8);
            pb2 = *(const uint4*)(Wt + (size_t)(n0 + br2) * DM_ + ko + bc * 8);
        }
        bfrag af[2], bfr[6];
#pragma unroll
        for (int mi = 0; mi < 2; ++mi)
            af[mi] = *(const bfrag*)(As + (wm * 32 + mi * 16 + l16) * 40 + quad * 8);
#pragma unroll
        for (int ni = 0; ni < 6; ++ni)
            bfr[ni] = *(const bfrag*)(Bs + (wn * 96 + ni * 16 + l16) * 40 + quad * 8);
#pragma unroll
        for (int mi = 0; mi < 2; ++mi)
#pragma unroll
            for (int ni = 0; ni < 6; ++ni)
                acc[mi][ni] = __builtin_amdgcn_mfma_f32_16x16x32_bf16(af[mi], bfr[ni], acc[mi][ni], 0, 0, 0);
    }

    // epilogue: C -> Cs (all 64 rows at once), coalesced uint4 stores.
    // Q columns (c%3==0) pre-scaled by 0.125*log2(e) so attn softmax is bare exp2.
    const int b  = m0 >> 11;
    const int tb = m0 & 2047;
    const size_t bh = (size_t)(b * 8 + h);
    float cscale[6];
#pragma unroll
    for (int ni = 0; ni < 6; ++ni) {
        int c = wn * 96 + ni * 16 + l16;
        cscale[ni] = (c % 3 == 0) ? SCALE_L2E : 1.0f;
    }
    __syncthreads();
#pragma unroll
    for (int mi = 0; mi < 2; ++mi)
#pragma unroll
        for (int ni = 0; ni < 6; ++ni)
#pragma unroll
            for (int reg = 0; reg < 4; ++reg) {
                int r = wm * 32 + mi * 16 + quad * 4 + reg;    // 0..63
                int c = wn * 96 + ni * 16 + l16;               // 0..191
                Cs[r * 200 + c] = f2bf_fast((acc[mi][ni][reg] + bvv[ni]) * cscale[ni]);
            }
    __syncthreads();
#pragma unroll
    for (int i = 0; i < 2; ++i) {
        int idx = tid + i * 256;            // 0..511
        int tl = idx >> 3, hc = (idx & 7) * 8;
        __align__(16) unsigned short tq[8], tk[8];
#pragma unroll
        for (int j = 0; j < 8; ++j) {
            tq[j] = Cs[tl * 200 + (hc + j) * 3 + 0];
            tk[j] = Cs[tl * 200 + (hc + j) * 3 + 1];
        }
        *(uint4*)(Qb + (bh * T_ + tb + tl) * HD_ + hc) = *(const uint4*)tq;
        *(uint4*)(Kb + (bh * T_ + tb + tl) * HD_ + hc) = *(const uint4*)tk;
    }
#pragma unroll
    for (int i = 0; i < 2; ++i) {
        int idx = tid + i * 256;
        int hd = idx >> 3, t8 = (idx & 7) * 8;
        __align__(16) unsigned short tv[8];
#pragma unroll
        for (int j = 0; j < 8; ++j)
            tv[j] = Cs[(t8 + j) * 200 + hd * 3 + 2];
        *(uint4*)(Vtb + (bh * HD_ + hd) * T_ + tb + t8) = *(const uint4*)tv;
    }
}

// ---------------------------------------------------------------------------
// Kernel 2: flash attention, 128-q-row tile, software-pipelined K/V staging
// (double LDS buffer, ONE barrier/kt). Flat grid bid = qt*32 + bh (XCD=bh%8).
// Mask flags read as one int4 per row-group per kt (OR of 4 quarter-flags).
// ---------------------------------------------------------------------------
__global__ __launch_bounds__(256) void k_attn(const unsigned short* __restrict__ Q,
                                              const unsigned short* __restrict__ K,
                                              const unsigned short* __restrict__ Vt,
                                              const float* __restrict__ mask,
                                              const int4* __restrict__ flags4,
                                              float* __restrict__ out) {
    __shared__ __align__(16) unsigned short Ks[2][64 * 72];
    __shared__ __align__(16) unsigned short Vs[2][64 * 72];   // [dim][kv]
    __shared__ __align__(16) unsigned short Ps[4][16 * 72];

    const int tid = threadIdx.x;
    const int wave = tid >> 6, lane = tid & 63;
    const int quad = lane >> 4, l16 = lane & 15;
    const int bh = blockIdx.x & 31, b = bh >> 3, h = bh & 7;
    const int qt = blockIdx.x >> 5;      // 0..15
    const int q0 = qt * 128;

    bfrag qf[2][2];
#pragma unroll
    for (int g = 0; g < 2; ++g) {
        size_t qrow = ((size_t)bh * T_ + q0 + wave * 32 + g * 16 + l16) * HD_;
        qf[g][0] = *(const bfrag*)(Q + qrow + quad * 8);
        qf[g][1] = *(const bfrag*)(Q + qrow + 32 + quad * 8);
    }
    float lsum[2][4] = {{0.f,0.f,0.f,0.f},{0.f,0.f,0.f,0.f}};
    ffrag of[2][4];
#pragma unroll
    for (int g = 0; g < 2; ++g)
#pragma unroll
        for (int nb = 0; nb < 4; ++nb) of[g][nb] = (ffrag){0.f, 0.f, 0.f, 0.f};

    const int e0 = b * 32 + qt * 2;
    const int e1 = e0 + 1;

    // staging geometry: chunk i covers row r=(tid+i*256)>>3, 16B col c=tid&7
    const int sr0 = tid >> 3, sr1 = (tid + 256) >> 3, sc = tid & 7;
    const unsigned short* Kbase = K  + (size_t)bh * T_ * HD_;
    const unsigned short* Vbase = Vt + (size_t)bh * HD_ * T_;

    uint4 kreg[2], vreg[2];
    kreg[0] = *(const uint4*)(Kbase + (size_t)sr0 * HD_ + sc * 8);
    kreg[1] = *(const uint4*)(Kbase + (size_t)sr1 * HD_ + sc * 8);
    vreg[0] = *(const uint4*)(Vbase + (size_t)sr0 * T_ + sc * 8);
    vreg[1] = *(const uint4*)(Vbase + (size_t)sr1 * T_ + sc * 8);
    *(uint4*)(&Ks[0][sr0 * 72 + sc * 8]) = kreg[0];
    *(uint4*)(&Ks[0][sr1 * 72 + sc * 8]) = kreg[1];
    *(uint4*)(&Vs[0][sr0 * 72 + sc * 8]) = vreg[0];
    *(uint4*)(&Vs[0][sr1 * 72 + sc * 8]) = vreg[1];
    __syncthreads();

    for (int kt = 0; kt < 32; ++kt) {
        const int cur = kt & 1;
        if (kt < 31) {                        // issue kt+1 loads (drain after compute)
            const int kn = (kt + 1) * 64;
            kreg[0] = *(const uint4*)(Kbase + (size_t)(kn + sr0) * HD_ + sc * 8);
            kreg[1] = *(const uint4*)(Kbase + (size_t)(kn + sr1) * HD_ + sc * 8);
            vreg[0] = *(const uint4*)(Vbase + (size_t)sr0 * T_ + kn + sc * 8);
            vreg[1] = *(const uint4*)(Vbase + (size_t)sr1 * T_ + kn + sc * 8);
        }
        int4 F0 = flags4[e0 * 32 + kt];
        int4 F1 = flags4[e1 * 32 + kt];
        int fl[2];
        fl[0] = F0.x | F0.y | F0.z | F0.w;
        fl[1] = F1.x | F1.y | F1.z | F1.w;

        bfrag vf[2][4];
#pragma unroll
        for (int ks = 0; ks < 2; ++ks)
#pragma unroll
            for (int nb = 0; nb < 4; ++nb)
                vf[ks][nb] = *(const bfrag*)(&Vs[cur][(nb * 16 + l16) * 72 + (ks * 4 + quad) * 8]);

#pragma unroll
        for (int g = 0; g < 2; ++g) {
            ffrag sf[4];
#pragma unroll
            for (int ns = 0; ns < 4; ++ns) {
                ffrag a = (ffrag){0.f, 0.f, 0.f, 0.f};
#pragma unroll
                for (int ks = 0; ks < 2; ++ks) {
                    bfrag kf = *(const bfrag*)(&Ks[cur][(ns * 16 + l16) * 72 + (ks * 4 + quad) * 8]);
                    a = __builtin_amdgcn_mfma_f32_16x16x32_bf16(qf[g][ks], kf, a, 0, 0, 0);
                }
                sf[ns] = a;
            }
            if (fl[g]) {
#pragma unroll
                for (int reg = 0; reg < 4; ++reg) {
                    int tq = q0 + wave * 32 + g * 16 + quad * 4 + reg;
                    const float* mrow = mask + ((size_t)b * T_ + tq) * T_ + kt * 64;
#pragma unroll
                    for (int ns = 0; ns < 4; ++ns) {
                        float msk = mrow[ns * 16 + l16];
                        float p = __builtin_amdgcn_exp2f(
                            fmaf(msk, MASK_L2E, sf[ns][reg] - MASK_L2E));
                        lsum[g][reg] += p;
                        Ps[wave][(quad * 4 + reg) * 72 + ns * 16 + l16] = f2bf_fast(p);
                    }
                }
            } else {
#pragma unroll
                for (int reg = 0; reg < 4; ++reg) {
#pragma unroll
                    for (int ns = 0; ns < 4; ++ns) {
                        float p = __builtin_amdgcn_exp2f(sf[ns][reg]);
                        lsum[g][reg] += p;
                        Ps[wave][(quad * 4 + reg) * 72 + ns * 16 + l16] = f2bf_fast(p);
                    }
                }
            }
#pragma unroll
            for (int ks = 0; ks < 2; ++ks) {
                bfrag pf = *(const bfrag*)(&Ps[wave][l16 * 72 + (ks * 4 + quad) * 8]);
#pragma unroll
                for (int nb = 0; nb < 4; ++nb)
                    of[g][nb] = __builtin_amdgcn_mfma_f32_16x16x32_bf16(pf, vf[ks][nb], of[g][nb], 0, 0, 0);
            }
        }
        if (kt < 31) {
            const int nxt = cur ^ 1;
            *(uint4*)(&Ks[nxt][sr0 * 72 + sc * 8]) = kreg[0];
            *(uint4*)(&Ks[nxt][sr1 * 72 + sc * 8]) = kreg[1];
            *(uint4*)(&Vs[nxt][sr0 * 72 + sc * 8]) = vreg[0];
            *(uint4*)(&Vs[nxt][sr1 * 72 + sc * 8]) = vreg[1];
            __syncthreads();
        }
    }
    // epilogue: shuffle-reduce row-sums, normalize, fp32 store
#pragma unroll
    for (int g = 0; g < 2; ++g)
#pragma unroll
    for (int reg = 0; reg < 4; ++reg) {
        float s = lsum[g][reg];
#pragma unroll
        for (int d = 1; d < 16; d <<= 1) s += __shfl_xor(s, d, 64);
        float inv = 1.0f / s;
        int t = q0 + wave * 32 + g * 16 + quad * 4 + reg;
#pragma unroll
        for (int nb = 0; nb < 4; ++nb)
            out[((size_t)b * T_ + t) * DM_ + h * 64 + nb * 16 + l16] = of[g][nb][reg] * inv;
    }
}

// ---------------------------------------------------------------------------
extern "C" void kernel_launch(void* const* d_in, const int* in_sizes, int n_in,
                              void* d_out, int out_size, void* d_ws, size_t ws_size,
                              hipStream_t stream) {
    const float* X    = (const float*)d_in[0];   // [4,2048,512] fp32
    const float* mask = (const float*)d_in[1];   // [4,1,2048,2048] fp32
    const float* W    = (const float*)d_in[2];   // [512,1536] fp32
    const float* bias = (const float*)d_in[3];   // [1536] fp32
    float* outp = (float*)d_out;                 // [4,2048,512] fp32

    char* ws = (char*)d_ws;
    unsigned short* Wt  = (unsigned short*)(ws);              // 1.5 MB
    unsigned short* Xb  = (unsigned short*)(ws + 1572864);    // 8 MB
    unsigned short* Qb  = (unsigned short*)(ws + 9961472);    // 8 MB
    unsigned short* Kb  = (unsigned short*)(ws + 18350080);   // 8 MB
    unsigned short* Vtb = (unsigned short*)(ws + 26738688);   // 8 MB
    int*            flg = (int*)(ws + 35127296);              // 64 KB (end ~35.2 MB)

    k_prep     <<<dim3(960),  256, 0, stream>>>(W, X, mask, Wt, Xb, flg);
    k_gemm_qkv <<<dim3(1024), 256, 0, stream>>>(Xb, Wt, bias, Qb, Kb, Vtb);
    k_attn     <<<dim3(512),  256, 0, stream>>>(Qb, Kb, Vtb, mask, (const int4*)flg, outp);
}